// Round 2
// baseline (212.169 us; speedup 1.0000x reference)
//
#include <hip/hip_runtime.h>

// SENet layer, fp32 NHWC. B=32, H=W=56 (HW=3136), C=256, C/R=16.
//  k1: partial spatial sums  -> ws partial [B*49][256] fp32
//  k2: reduce + MLP (relu, sigmoid) -> ws g [B][256] fp32
//  k3: out = x * g (broadcast over spatial)

#define BATCH 32
#define HW 3136
#define C 256
#define CR 16
#define SBLK 49            // spatial blocks per batch (3136/64 rows)
#define VPR 64             // float4 vectors per row (256 floats / 4)

// ---------------- kernel 1: partial pooling sums ----------------
__global__ __launch_bounds__(256) void se_pool_partial(
        const float* __restrict__ x, float* __restrict__ partial) {
    const int b    = blockIdx.x / SBLK;
    const int sblk = blockIdx.x % SBLK;
    const int tid  = threadIdx.x;
    const int lane = tid & 63;   // float4 index within a row (0..63)
    const int rg   = tid >> 6;   // row group (0..3)

    const float4* __restrict__ xv = (const float4*)x;
    const int row0 = sblk * 64;

    float4 a = make_float4(0.f, 0.f, 0.f, 0.f);
#pragma unroll
    for (int k = 0; k < 16; ++k) {
        const int r = row0 + rg + 4 * k;
        float4 v = xv[(size_t)(b * HW + r) * VPR + lane];
        a.x += v.x; a.y += v.y; a.z += v.z; a.w += v.w;
    }

    __shared__ float red[256 * 4];
    red[tid * 4 + 0] = a.x;
    red[tid * 4 + 1] = a.y;
    red[tid * 4 + 2] = a.z;
    red[tid * 4 + 3] = a.w;
    __syncthreads();

    if (tid < 64) {
#pragma unroll
        for (int gg = 1; gg < 4; ++gg) {
            a.x += red[(gg * 64 + tid) * 4 + 0];
            a.y += red[(gg * 64 + tid) * 4 + 1];
            a.z += red[(gg * 64 + tid) * 4 + 2];
            a.w += red[(gg * 64 + tid) * 4 + 3];
        }
        float* dst = partial + (size_t)(b * SBLK + sblk) * C + tid * 4;
        dst[0] = a.x; dst[1] = a.y; dst[2] = a.z; dst[3] = a.w;
    }
}

// ---------------- kernel 2: reduce partials + MLP ----------------
__global__ __launch_bounds__(256) void se_mlp(
        const float* __restrict__ partial,
        const float* __restrict__ w1, const float* __restrict__ b1,
        const float* __restrict__ w2, const float* __restrict__ b2,
        float* __restrict__ g) {
    const int b = blockIdx.x;
    const int c = threadIdx.x;

    __shared__ float s[C];
    __shared__ float h[CR];

    float sum = 0.f;
#pragma unroll 7
    for (int k = 0; k < SBLK; ++k) sum += partial[(size_t)(b * SBLK + k) * C + c];
    s[c] = sum * (1.0f / (float)HW);
    __syncthreads();

    if (c < CR) {
        float acc = b1[c];
        for (int k = 0; k < C; ++k) acc += s[k] * w1[k * CR + c];
        h[c] = fmaxf(acc, 0.f);
    }
    __syncthreads();

    float acc = b2[c];
#pragma unroll
    for (int j = 0; j < CR; ++j) acc += h[j] * w2[j * C + c];
    g[b * C + c] = 1.f / (1.f + expf(-acc));
}

// ---------------- kernel 3: scale ----------------
__global__ __launch_bounds__(256) void se_scale(
        const float* __restrict__ x, const float* __restrict__ g,
        float* __restrict__ out) {
    const int b    = blockIdx.x / SBLK;
    const int sblk = blockIdx.x % SBLK;
    const int tid  = threadIdx.x;

    // float4 vectors: per batch = HW*VPR = 200704; per block = 4096; per thread = 16
    const size_t base = (size_t)b * (HW * VPR) + (size_t)sblk * 4096;

    // channel-group is invariant across this thread's iterations:
    // (base + tid + k*256) % 64 == tid % 64  (all strides are multiples of 64)
    const int c0 = (tid & 63) * 4;
    const float g0 = g[b * C + c0 + 0];
    const float g1 = g[b * C + c0 + 1];
    const float g2 = g[b * C + c0 + 2];
    const float g3 = g[b * C + c0 + 3];

    const float4* __restrict__ xv = (const float4*)x;
    float4* __restrict__ ov = (float4*)out;

#pragma unroll
    for (int k = 0; k < 16; ++k) {
        const size_t p = base + tid + (size_t)k * 256;
        float4 v = xv[p];
        v.x *= g0; v.y *= g1; v.z *= g2; v.w *= g3;
        ov[p] = v;
    }
}

extern "C" void kernel_launch(void* const* d_in, const int* in_sizes, int n_in,
                              void* d_out, int out_size, void* d_ws, size_t ws_size,
                              hipStream_t stream) {
    const float* x  = (const float*)d_in[0];
    const float* w1 = (const float*)d_in[1];
    const float* b1 = (const float*)d_in[2];
    const float* w2 = (const float*)d_in[3];
    const float* b2 = (const float*)d_in[4];
    float* out = (float*)d_out;

    float* partial = (float*)d_ws;                       // B*SBLK*C floats = 1.6 MB
    float* g       = partial + (size_t)BATCH * SBLK * C; // B*C floats = 32 KB

    se_pool_partial<<<dim3(BATCH * SBLK), dim3(256), 0, stream>>>(x, partial);
    se_mlp<<<dim3(BATCH), dim3(256), 0, stream>>>(partial, w1, b1, w2, b2, g);
    se_scale<<<dim3(BATCH * SBLK), dim3(256), 0, stream>>>(x, g, out);
}

// Round 4
// 207.362 us; speedup vs baseline: 1.0232x; 1.0232x over previous
//
#include <hip/hip_runtime.h>

// SENet layer, fp32 NHWC. B=32, H=W=56 (HW=3136), C=256, C/R=16.
//  A: partial spatial sums -> ws partial [B*49][256] fp32
//  B: per-(b,sblk) block: reduce partials + MLP (redundant per block, L2-hit)
//     then out = x * g for its 64-row tile.

#define BATCH 32
#define HW 3136
#define C 256
#define CR 16
#define SBLK 49            // spatial blocks per batch (3136/64 rows)
#define VPR 64             // float4 vectors per row (256 floats / 4)

typedef float v4f __attribute__((ext_vector_type(4)));  // native vec: OK for nontemporal builtins

// ---------------- kernel A: partial pooling sums ----------------
__global__ __launch_bounds__(256) void se_pool_partial(
        const float* __restrict__ x, float* __restrict__ partial) {
    const int b    = blockIdx.x / SBLK;
    const int sblk = blockIdx.x % SBLK;
    const int tid  = threadIdx.x;
    const int lane = tid & 63;   // float4 index within a row (0..63)
    const int rg   = tid >> 6;   // row group (0..3)

    const v4f* __restrict__ xv = (const v4f*)x;
    const int row0 = sblk * 64;

    v4f a = (v4f)(0.f);
#pragma unroll
    for (int k = 0; k < 16; ++k) {
        const int r = row0 + rg + 4 * k;
        a += xv[(size_t)(b * HW + r) * VPR + lane];
    }

    __shared__ float red[256 * 4];
    red[tid * 4 + 0] = a.x;
    red[tid * 4 + 1] = a.y;
    red[tid * 4 + 2] = a.z;
    red[tid * 4 + 3] = a.w;
    __syncthreads();

    if (tid < 64) {
#pragma unroll
        for (int gg = 1; gg < 4; ++gg) {
            a.x += red[(gg * 64 + tid) * 4 + 0];
            a.y += red[(gg * 64 + tid) * 4 + 1];
            a.z += red[(gg * 64 + tid) * 4 + 2];
            a.w += red[(gg * 64 + tid) * 4 + 3];
        }
        float* dst = partial + (size_t)(b * SBLK + sblk) * C + tid * 4;
        dst[0] = a.x; dst[1] = a.y; dst[2] = a.z; dst[3] = a.w;
    }
}

// ---------------- kernel B: reduce + MLP (per-block) + scale ----------------
__global__ __launch_bounds__(256) void se_mlp_scale(
        const float* __restrict__ x, const float* __restrict__ partial,
        const float* __restrict__ w1, const float* __restrict__ b1,
        const float* __restrict__ w2, const float* __restrict__ b2,
        float* __restrict__ out) {
    const int b    = blockIdx.x / SBLK;
    const int sblk = blockIdx.x % SBLK;
    const int tid  = threadIdx.x;

    __shared__ float s[C];
    __shared__ float red[C];
    __shared__ float h[CR];
    __shared__ float gl[C];

    // pooled mean for batch b (49 partials, L2-resident: shared by 49 blocks)
    {
        float sum = 0.f;
        const float* pb = partial + (size_t)b * SBLK * C + tid;
#pragma unroll 7
        for (int k = 0; k < SBLK; ++k) sum += pb[k * C];
        s[tid] = sum * (1.0f / (float)HW);
    }
    __syncthreads();

    // layer 1: h = relu(s @ w1 + b1).  16 outputs x 16 reduction lanes.
    // w1 reads at address t*256 + tid per step t: fully coalesced.
    {
        const int j = tid & 15;
        const int i = tid >> 4;
        float a = 0.f;
#pragma unroll
        for (int t = 0; t < 16; ++t) {
            const int k = t * 16 + i;
            a += s[k] * w1[k * CR + j];
        }
        red[tid] = a;
    }
    __syncthreads();
    if (tid < CR) {
        float acc = b1[tid];
#pragma unroll
        for (int i2 = 0; i2 < 16; ++i2) acc += red[i2 * 16 + tid];
        h[tid] = fmaxf(acc, 0.f);
    }
    __syncthreads();

    // layer 2: g = sigmoid(h @ w2 + b2), one channel per thread, coalesced w2.
    {
        float acc = b2[tid];
#pragma unroll
        for (int t = 0; t < CR; ++t) acc += h[t] * w2[t * C + tid];
        gl[tid] = 1.f / (1.f + expf(-acc));
    }
    __syncthreads();

    // scale this block's 64-row tile.
    // float4 vectors: per batch = HW*VPR = 200704; per block = 4096; per thread = 16
    const size_t base = (size_t)b * (HW * VPR) + (size_t)sblk * 4096;
    const int c0 = (tid & 63) * 4;   // channel group invariant across iterations
    const float g0 = gl[c0 + 0];
    const float g1 = gl[c0 + 1];
    const float g2 = gl[c0 + 2];
    const float g3 = gl[c0 + 3];

    const v4f* __restrict__ xv = (const v4f*)x;
    v4f* __restrict__ ov = (v4f*)out;

#pragma unroll
    for (int k = 0; k < 16; ++k) {
        const size_t p = base + tid + (size_t)k * 256;
        v4f v = __builtin_nontemporal_load(&xv[p]);   // last use of x
        v.x *= g0; v.y *= g1; v.z *= g2; v.w *= g3;
        __builtin_nontemporal_store(v, &ov[p]);       // never re-read
    }
}

extern "C" void kernel_launch(void* const* d_in, const int* in_sizes, int n_in,
                              void* d_out, int out_size, void* d_ws, size_t ws_size,
                              hipStream_t stream) {
    const float* x  = (const float*)d_in[0];
    const float* w1 = (const float*)d_in[1];
    const float* b1 = (const float*)d_in[2];
    const float* w2 = (const float*)d_in[3];
    const float* b2 = (const float*)d_in[4];
    float* out = (float*)d_out;

    float* partial = (float*)d_ws;   // B*SBLK*C floats = 1.6 MB

    se_pool_partial<<<dim3(BATCH * SBLK), dim3(256), 0, stream>>>(x, partial);
    se_mlp_scale<<<dim3(BATCH * SBLK), dim3(256), 0, stream>>>(
        x, partial, w1, b1, w2, b2, out);
}